// Round 5
// baseline (101.716 us; speedup 1.0000x reference)
//
#include <hip/hip_runtime.h>
#include <stdint.h>

#define N_ROWS 8192
#define D_DIM  1024
#define NEG_BIG -1e30f
#define NCHUNK 8
#define CHUNK_J 1024
#define NTILE 32            // 32 j-cols per tile, 32 tiles per chunk
#define BUFSZ (32 * 1024)   // 32 rows x 1024 B, swizzled (16B-slot XOR) layout

typedef __attribute__((ext_vector_type(16))) float f32x16;
typedef __attribute__((ext_vector_type(8)))  int   i32x8;
typedef __attribute__((ext_vector_type(2)))  long  long2_t;

// log2(e) * 10 : exp(10v - 10) = exp2(v*C - C)
#define EXPC 14.4269504089f
#define EXPV(v) exp2f(fmaf((v), EXPC, -EXPC))

// branchless sorted insert of v into descending 5-list, med3 form (5 ops)
#define INS5(b0,b1,b2,b3,b4,v) {                        \
    float _n4 = __builtin_amdgcn_fmed3f(b3, (v), b4);   \
    float _n3 = __builtin_amdgcn_fmed3f(b2, (v), b3);   \
    float _n2 = __builtin_amdgcn_fmed3f(b1, (v), b2);   \
    float _n1 = __builtin_amdgcn_fmed3f(b0, (v), b1);   \
    b0 = fmaxf(b0, (v)); b1 = _n1; b2 = _n2; b3 = _n3; b4 = _n4; }

// f32 -> OCP e4m3fn, RNE, with denormals. |x| <= ~1 here (normalized rows).
static __device__ inline uint32_t f2e4m3(float x) {
    uint32_t u = __float_as_uint(x);
    uint32_t s = (u >> 24) & 0x80u;
    uint32_t a = u & 0x7fffffffu;
    uint32_t e = a >> 23;
    uint32_t out;
    if (e >= 121u) {
        uint32_t mant = a & 0x7fffffu;
        uint32_t comb = ((e - 120u) << 3) | (mant >> 20);
        uint32_t rem  = mant & 0xfffffu;
        comb += (rem > 0x80000u) || ((rem == 0x80000u) && (comb & 1u));
        out = comb;
    } else {
        float scl = __uint_as_float(a) * 512.0f;
        out = (uint32_t)(int)rintf(scl);
    }
    return s | out;
}

// ---------------- K1: row-normalize f32 -> fp8 e4m3 ----------------
__global__ __launch_bounds__(256) void norm_kernel(const float* __restrict__ z,
                                                   uint8_t* __restrict__ zn8) {
    int wave = threadIdx.x >> 6;
    int lane = threadIdx.x & 63;
    int row  = blockIdx.x * 4 + wave;
    const float* zr = z + (size_t)row * D_DIM;
    float4 c[4];
    float ss = 0.f;
#pragma unroll
    for (int i = 0; i < 4; ++i) {
        c[i] = *(const float4*)(zr + i * 256 + lane * 4);
        ss += c[i].x*c[i].x + c[i].y*c[i].y + c[i].z*c[i].z + c[i].w*c[i].w;
    }
#pragma unroll
    for (int m = 1; m < 64; m <<= 1) ss += __shfl_xor(ss, m);
    float scale = 1.0f / fmaxf(sqrtf(ss), 1e-12f);
    uint8_t* zo = zn8 + (size_t)row * D_DIM;
#pragma unroll
    for (int i = 0; i < 4; ++i) {
        uint32_t d = f2e4m3(c[i].x * scale)
                   | (f2e4m3(c[i].y * scale) << 8)
                   | (f2e4m3(c[i].z * scale) << 16)
                   | (f2e4m3(c[i].w * scale) << 24);
        *(uint32_t*)(zo + i * 256 + lane * 4) = d;
    }
}

// ---------------- K2: fused fp8 sim via scale-MFMA K=64 ----------------
// grid: 64 i-blocks (128 rows, 32/wave) x 8 j-chunks (1024 cols).
// Swapped MFMA: A = streamed j-tile (LDS), B = resident i-rows.
// mfma_scale_f32_32x32x64_f8f6f4 with unit scales (E8M0 127).
// LDS swizzle: 16B-slot s of row jr holds global slot s ^ (jr&7) (full 3-bit
// involution -> reads hit all 8 slot-groups = all 32 banks, conflict-free).
// Read: MFMA m needs global slots {4m+2h, 4m+2h+1} of row r32 -> LDS slots
// (4m+2h)^(r32&7) and that ^1; two b128 reads via precomputed roff0/roff1.
__global__ __launch_bounds__(256, 2) void sim_kernel(const uint8_t* __restrict__ zn8,
                                                     float* __restrict__ pstats) {
    __shared__ __align__(16) char lds[2 * BUFSZ];
    const int tid  = threadIdx.x;
    const int w    = tid >> 6;
    const int l    = tid & 63;
    const int r32  = l & 31;
    const int h    = l >> 5;
    const int f3   = r32 & 7;
    const int ib   = blockIdx.x >> 3;
    const int ch   = blockIdx.x & 7;
    const int i0w  = ib * 128 + w * 32;
    const int j0c  = ch * CHUNK_J;
    const int i_lane = i0w + r32;
    const int diag_jt = (ch == (ib >> 3)) ? ((ib & 7) * 4 + w) : -1;

    // persistent per-lane LDS read offsets
    int roff0[16], roff1[16];
#pragma unroll
    for (int m = 0; m < 16; ++m) {
        roff0[m] = r32 * 1024 + (((4 * m + 2 * h) ^ f3) << 4);
        roff1[m] = roff0[m] ^ 16;
    }

    // prologue: stage tile 0 into buffer 0
#pragma unroll
    for (int u = 0; u < 8; ++u) {
        int jr = w * 8 + u;
        const uint8_t* src = zn8 + (size_t)(j0c + jr) * D_DIM + ((l ^ (jr & 7)) << 4);
        char* dst = lds + jr * 1024;
        __builtin_amdgcn_global_load_lds(
            (const __attribute__((address_space(1))) uint32_t*)src,
            (__attribute__((address_space(3))) uint32_t*)dst, 16, 0, 0);
    }

    // resident B-operand: lane holds col i_lane; bres[m] = k bytes [m*64+h*32, +32)
    i32x8 bres[16];
    {
        const uint8_t* rp = zn8 + (size_t)i_lane * D_DIM + h * 32;
#pragma unroll
        for (int m = 0; m < 16; ++m) {
            *(long2_t*)&bres[m]       = *(const long2_t*)(rp + m * 64);
            *((long2_t*)&bres[m] + 1) = *(const long2_t*)(rp + m * 64 + 16);
        }
    }

    float s0r = 0.f, s1r = 0.f;
    float b0 = NEG_BIG, b1 = NEG_BIG, b2 = NEG_BIG, b3 = NEG_BIG, b4 = NEG_BIG;

    __syncthreads();

#define TILE_BODY(JT, CUR) {                                                    \
        if ((JT) + 1 < NTILE) {                                                 \
            const int jb_ = j0c + ((JT) + 1) * 32;                              \
            char* bufn_ = lds + ((CUR) ^ BUFSZ);                                \
            _Pragma("unroll")                                                   \
            for (int u = 0; u < 8; ++u) {                                       \
                int jr = w * 8 + u;                                             \
                const uint8_t* src = zn8 + (size_t)(jb_ + jr) * D_DIM           \
                                     + ((l ^ (jr & 7)) << 4);                   \
                char* dst = bufn_ + jr * 1024;                                  \
                __builtin_amdgcn_global_load_lds(                               \
                    (const __attribute__((address_space(1))) uint32_t*)src,     \
                    (__attribute__((address_space(3))) uint32_t*)dst, 16, 0, 0);\
            }                                                                   \
        }                                                                       \
        f32x16 acc0, acc1;                                                      \
        _Pragma("unroll")                                                       \
        for (int r = 0; r < 16; ++r) { acc0[r] = 0.f; acc1[r] = 0.f; }          \
        __builtin_amdgcn_s_setprio(1);                                          \
        _Pragma("unroll")                                                       \
        for (int m = 0; m < 16; ++m) {                                          \
            asm volatile("" : "+v"(bres[m]));  /* keep resident */              \
            i32x8 a;                                                            \
            *(long2_t*)&a       = *(const long2_t*)(lds + (CUR) + roff0[m]);    \
            *((long2_t*)&a + 1) = *(const long2_t*)(lds + (CUR) + roff1[m]);    \
            if (m & 1)                                                          \
                acc1 = __builtin_amdgcn_mfma_scale_f32_32x32x64_f8f6f4(         \
                    a, bres[m], acc1, 0, 0, 0, 127, 0, 127);                    \
            else                                                                \
                acc0 = __builtin_amdgcn_mfma_scale_f32_32x32x64_f8f6f4(         \
                    a, bres[m], acc0, 0, 0, 0, 127, 0, 127);                    \
        }                                                                       \
        __builtin_amdgcn_s_setprio(0);                                          \
        if ((JT) != diag_jt) {                                                  \
            _Pragma("unroll")                                                   \
            for (int r = 0; r < 16; ++r) {                                      \
                float v = acc0[r] + acc1[r];                                    \
                INS5(b0, b1, b2, b3, b4, v);                                    \
                if (r & 1) s1r += EXPV(v); else s0r += EXPV(v);                 \
            }                                                                   \
        } else {                                                                \
            const int dd2 = i_lane - (j0c + (JT) * 32) - 4 * h;                 \
            _Pragma("unroll")                                                   \
            for (int r = 0; r < 16; ++r) {                                      \
                const int jm = (r & 3) + 8 * (r >> 2);                          \
                float v = acc0[r] + acc1[r];                                    \
                if (dd2 == jm) v = NEG_BIG;                                     \
                INS5(b0, b1, b2, b3, b4, v);                                    \
                if (r & 1) s1r += EXPV(v); else s0r += EXPV(v);                 \
            }                                                                   \
        }                                                                       \
        __syncthreads();                                                        \
    }

    for (int jt = 0; jt < NTILE; jt += 2) {
        TILE_BODY(jt, 0);
        TILE_BODY(jt + 1, BUFSZ);
    }
#undef TILE_BODY

    float s_run = s0r + s1r;
    // merge the two h-halves: lanes l and l^32 hold complementary j-rows of col i
    s_run += __shfl_xor(s_run, 32);
    {
        float o0 = __shfl_xor(b0, 32), o1 = __shfl_xor(b1, 32), o2 = __shfl_xor(b2, 32),
              o3 = __shfl_xor(b3, 32), o4 = __shfl_xor(b4, 32);
        INS5(b0, b1, b2, b3, b4, o0); INS5(b0, b1, b2, b3, b4, o1);
        INS5(b0, b1, b2, b3, b4, o2); INS5(b0, b1, b2, b3, b4, o3);
        INS5(b0, b1, b2, b3, b4, o4);
    }
    if (h == 0) {
        float* p = pstats + ((size_t)ch * N_ROWS + i_lane) * 8;
        p[0] = s_run; p[1] = b0; p[2] = b1; p[3] = b2; p[4] = b3; p[5] = b4;
        p[6] = 0.f; p[7] = 0.f;
    }
}

// ---------------- K3: per-row merge of 8 chunk partials ----------------
__global__ __launch_bounds__(128) void reduce1(const float* __restrict__ pstats,
                                               float* __restrict__ partial) {
    int row = blockIdx.x * 128 + threadIdx.x;
    float S = 0.f;
    float b0 = NEG_BIG, b1 = NEG_BIG, b2 = NEG_BIG, b3 = NEG_BIG, b4 = NEG_BIG;
#pragma unroll
    for (int c = 0; c < NCHUNK; ++c) {
        const float* p = pstats + ((size_t)c * N_ROWS + row) * 8;
        S += p[0];
        float v0 = p[1], v1 = p[2], v2 = p[3], v3 = p[4], v4 = p[5];
        INS5(b0, b1, b2, b3, b4, v0); INS5(b0, b1, b2, b3, b4, v1);
        INS5(b0, b1, b2, b3, b4, v2); INS5(b0, b1, b2, b3, b4, v3);
        INS5(b0, b1, b2, b3, b4, v4);
    }
    float S5 = EXPV(b0) + EXPV(b1) + EXPV(b2) + EXPV(b3) + EXPV(b4);
    float loss = __logf(S) - __logf(S5);
#pragma unroll
    for (int m = 1; m < 64; m <<= 1) loss += __shfl_xor(loss, m);
    __shared__ float rr[2];
    if ((threadIdx.x & 63) == 0) rr[threadIdx.x >> 6] = loss;
    __syncthreads();
    if (threadIdx.x == 0) partial[blockIdx.x] = rr[0] + rr[1];
}

// ---------------- K4: final mean ----------------
__global__ void reduce2(const float* __restrict__ partial, float* __restrict__ out) {
    float v = partial[threadIdx.x];   // 64 partials
#pragma unroll
    for (int m = 1; m < 64; m <<= 1) v += __shfl_xor(v, m);
    if (threadIdx.x == 0) out[0] = v * (1.0f / N_ROWS);
}

extern "C" void kernel_launch(void* const* d_in, const int* in_sizes, int n_in,
                              void* d_out, int out_size, void* d_ws, size_t ws_size,
                              hipStream_t stream) {
    const float* z = (const float*)d_in[0];
    float* out = (float*)d_out;
    uint8_t* zn8   = (uint8_t*)d_ws;                                   // 8 MB
    float* pstats  = (float*)((char*)d_ws + (size_t)8 * 1024 * 1024);  // 2 MB
    float* partial = (float*)((char*)d_ws + (size_t)10 * 1024 * 1024); // 256 B

    norm_kernel<<<N_ROWS / 4, 256, 0, stream>>>(z, zn8);
    sim_kernel<<<64 * NCHUNK, 256, 0, stream>>>(zn8, pstats);
    reduce1<<<N_ROWS / 128, 128, 0, stream>>>(pstats, partial);
    reduce2<<<1, 64, 0, stream>>>(partial, out);
}

// Round 6
// 93.982 us; speedup vs baseline: 1.0823x; 1.0823x over previous
//
#include <hip/hip_runtime.h>
#include <stdint.h>

#define N_ROWS 8192
#define D_DIM  1024
#define NEG_BIG -1e30f
#define NCHUNK 8
#define CHUNK_J 1024
#define NTILE 32            // 32 j-cols per tile, 32 tiles per chunk
#define BUFSZ (32 * 1024)   // 32 rows x 1024 B, swizzled (16B-slot XOR) layout

typedef __attribute__((ext_vector_type(16))) float f32x16;
typedef __attribute__((ext_vector_type(8)))  int   i32x8;
typedef __attribute__((ext_vector_type(2)))  long  long2_t;

// log2(e) * 10 : exp(10v - 10) = exp2(v*C - C)
#define EXPC 14.4269504089f
#define EXPV(v) exp2f(fmaf((v), EXPC, -EXPC))

// branchless sorted insert of v into descending 5-list, med3 form (5 ops)
#define INS5(b0,b1,b2,b3,b4,v) {                        \
    float _n4 = __builtin_amdgcn_fmed3f(b3, (v), b4);   \
    float _n3 = __builtin_amdgcn_fmed3f(b2, (v), b3);   \
    float _n2 = __builtin_amdgcn_fmed3f(b1, (v), b2);   \
    float _n1 = __builtin_amdgcn_fmed3f(b0, (v), b1);   \
    b0 = fmaxf(b0, (v)); b1 = _n1; b2 = _n2; b3 = _n3; b4 = _n4; }

// f32 -> OCP e4m3fn, RNE, with denormals. |x| <= ~1 here (normalized rows).
static __device__ inline uint32_t f2e4m3(float x) {
    uint32_t u = __float_as_uint(x);
    uint32_t s = (u >> 24) & 0x80u;
    uint32_t a = u & 0x7fffffffu;
    uint32_t e = a >> 23;
    uint32_t out;
    if (e >= 121u) {
        uint32_t mant = a & 0x7fffffu;
        uint32_t comb = ((e - 120u) << 3) | (mant >> 20);
        uint32_t rem  = mant & 0xfffffu;
        comb += (rem > 0x80000u) || ((rem == 0x80000u) && (comb & 1u));
        out = comb;
    } else {
        float scl = __uint_as_float(a) * 512.0f;
        out = (uint32_t)(int)rintf(scl);
    }
    return s | out;
}

// ---------------- K1: row-normalize f32 -> fp8 e4m3 ----------------
__global__ __launch_bounds__(256) void norm_kernel(const float* __restrict__ z,
                                                   uint8_t* __restrict__ zn8) {
    int wave = threadIdx.x >> 6;
    int lane = threadIdx.x & 63;
    int row  = blockIdx.x * 4 + wave;
    const float* zr = z + (size_t)row * D_DIM;
    float4 c[4];
    float ss = 0.f;
#pragma unroll
    for (int i = 0; i < 4; ++i) {
        c[i] = *(const float4*)(zr + i * 256 + lane * 4);
        ss += c[i].x*c[i].x + c[i].y*c[i].y + c[i].z*c[i].z + c[i].w*c[i].w;
    }
#pragma unroll
    for (int m = 1; m < 64; m <<= 1) ss += __shfl_xor(ss, m);
    float scale = 1.0f / fmaxf(sqrtf(ss), 1e-12f);
    uint8_t* zo = zn8 + (size_t)row * D_DIM;
#pragma unroll
    for (int i = 0; i < 4; ++i) {
        uint32_t d = f2e4m3(c[i].x * scale)
                   | (f2e4m3(c[i].y * scale) << 8)
                   | (f2e4m3(c[i].z * scale) << 16)
                   | (f2e4m3(c[i].w * scale) << 24);
        *(uint32_t*)(zo + i * 256 + lane * 4) = d;
    }
}

// ---------------- K2: fused fp8 sim via scale-MFMA K=64 ----------------
// grid: 64 i-blocks (128 rows, 32/wave) x 8 j-chunks (1024 cols).
// Swapped MFMA: A = streamed j-tile (LDS), B = resident i-rows.
// LDS swizzle: 16B-slot s of row jr holds global slot s^(jr&7) (full 3-bit
// involution -> every b128 read spreads over all 8 slot-groups = 32 banks).
// Read addressing: byte(m) = r32*1024 + 128*(m>>1) + 64*((m&1)^b2)
//                          + 32*(h^b1) + 16*b0   (f3 = b2 b1 b0 = r32&7)
// -> 4 per-lane base pointers (e0, e0^16, e0^64, e0^80); the 128*(m>>1)+CUR
// part is a compile-time ds_read offset immediate. 4 addr VGPRs, no spills.
__global__ __launch_bounds__(256, 2) void sim_kernel(const uint8_t* __restrict__ zn8,
                                                     float* __restrict__ pstats) {
    __shared__ __align__(16) char lds[2 * BUFSZ];
    const int tid  = threadIdx.x;
    const int w    = tid >> 6;
    const int l    = tid & 63;
    const int r32  = l & 31;
    const int h    = l >> 5;
    const int f3   = r32 & 7;
    const int ib   = blockIdx.x >> 3;
    const int ch   = blockIdx.x & 7;
    const int i0w  = ib * 128 + w * 32;
    const int j0c  = ch * CHUNK_J;
    const int i_lane = i0w + r32;
    const int diag_jt = (ch == (ib >> 3)) ? ((ib & 7) * 4 + w) : -1;

    // 4 per-lane LDS read base pointers
    const int b0f = f3 & 1, b1f = (f3 >> 1) & 1, b2f = f3 >> 2;
    const int e0 = r32 * 1024 + (b2f << 6) + ((h ^ b1f) << 5) + (b0f << 4);
    const char* a00 = lds + e0;          // even m, low 16B
    const char* a01 = lds + (e0 ^ 16);   // even m, high 16B
    const char* a10 = lds + (e0 ^ 64);   // odd m, low 16B
    const char* a11 = lds + (e0 ^ 80);   // odd m, high 16B

    // prologue: stage tile 0 into buffer 0
#pragma unroll
    for (int u = 0; u < 8; ++u) {
        int jr = w * 8 + u;
        const uint8_t* src = zn8 + (size_t)(j0c + jr) * D_DIM + ((l ^ (jr & 7)) << 4);
        char* dst = lds + jr * 1024;
        __builtin_amdgcn_global_load_lds(
            (const __attribute__((address_space(1))) uint32_t*)src,
            (__attribute__((address_space(3))) uint32_t*)dst, 16, 0, 0);
    }

    // resident B-operand: lane holds col i_lane; bres[m] = k bytes [m*64+h*32, +32)
    i32x8 bres[16];
    {
        const uint8_t* rp = zn8 + (size_t)i_lane * D_DIM + h * 32;
#pragma unroll
        for (int m = 0; m < 16; ++m) {
            *(long2_t*)&bres[m]       = *(const long2_t*)(rp + m * 64);
            *((long2_t*)&bres[m] + 1) = *(const long2_t*)(rp + m * 64 + 16);
        }
    }

    float s0r = 0.f, s1r = 0.f;
    float b0 = NEG_BIG, b1 = NEG_BIG, b2 = NEG_BIG, b3 = NEG_BIG, b4 = NEG_BIG;

    __syncthreads();

#define TILE_BODY(JT, CUR) {                                                    \
        if ((JT) + 1 < NTILE) {                                                 \
            const int jb_ = j0c + ((JT) + 1) * 32;                              \
            char* bufn_ = lds + ((CUR) ^ BUFSZ);                                \
            _Pragma("unroll")                                                   \
            for (int u = 0; u < 8; ++u) {                                       \
                int jr = w * 8 + u;                                             \
                const uint8_t* src = zn8 + (size_t)(jb_ + jr) * D_DIM           \
                                     + ((l ^ (jr & 7)) << 4);                   \
                char* dst = bufn_ + jr * 1024;                                  \
                __builtin_amdgcn_global_load_lds(                               \
                    (const __attribute__((address_space(1))) uint32_t*)src,     \
                    (__attribute__((address_space(3))) uint32_t*)dst, 16, 0, 0);\
            }                                                                   \
        }                                                                       \
        f32x16 acc0, acc1;                                                      \
        _Pragma("unroll")                                                       \
        for (int r = 0; r < 16; ++r) { acc0[r] = 0.f; acc1[r] = 0.f; }          \
        __builtin_amdgcn_s_setprio(1);                                          \
        _Pragma("unroll")                                                       \
        for (int m = 0; m < 16; ++m) {                                          \
            asm volatile("" : "+v"(bres[m]));  /* keep resident */              \
            const char* pl_ = (m & 1) ? a10 : a00;                              \
            const char* ph_ = (m & 1) ? a11 : a01;                              \
            i32x8 a;                                                            \
            *(long2_t*)&a       = *(const long2_t*)(pl_ + (CUR) + (m >> 1) * 128);\
            *((long2_t*)&a + 1) = *(const long2_t*)(ph_ + (CUR) + (m >> 1) * 128);\
            if (m & 1)                                                          \
                acc1 = __builtin_amdgcn_mfma_scale_f32_32x32x64_f8f6f4(         \
                    a, bres[m], acc1, 0, 0, 0, 127, 0, 127);                    \
            else                                                                \
                acc0 = __builtin_amdgcn_mfma_scale_f32_32x32x64_f8f6f4(         \
                    a, bres[m], acc0, 0, 0, 0, 127, 0, 127);                    \
        }                                                                       \
        __builtin_amdgcn_s_setprio(0);                                          \
        if ((JT) != diag_jt) {                                                  \
            _Pragma("unroll")                                                   \
            for (int r = 0; r < 16; ++r) {                                      \
                float v = acc0[r] + acc1[r];                                    \
                INS5(b0, b1, b2, b3, b4, v);                                    \
                if (r & 1) s1r += EXPV(v); else s0r += EXPV(v);                 \
            }                                                                   \
        } else {                                                                \
            const int dd2 = i_lane - (j0c + (JT) * 32) - 4 * h;                 \
            _Pragma("unroll")                                                   \
            for (int r = 0; r < 16; ++r) {                                      \
                const int jm = (r & 3) + 8 * (r >> 2);                          \
                float v = acc0[r] + acc1[r];                                    \
                if (dd2 == jm) v = NEG_BIG;                                     \
                INS5(b0, b1, b2, b3, b4, v);                                    \
                if (r & 1) s1r += EXPV(v); else s0r += EXPV(v);                 \
            }                                                                   \
        }                                                                       \
        __syncthreads();                                                        \
    }

    for (int jt = 0; jt < NTILE; jt += 2) {
        TILE_BODY(jt, 0);
        TILE_BODY(jt + 1, BUFSZ);
    }
#undef TILE_BODY

    float s_run = s0r + s1r;
    // merge the two h-halves: lanes l and l^32 hold complementary j-rows of col i
    s_run += __shfl_xor(s_run, 32);
    {
        float o0 = __shfl_xor(b0, 32), o1 = __shfl_xor(b1, 32), o2 = __shfl_xor(b2, 32),
              o3 = __shfl_xor(b3, 32), o4 = __shfl_xor(b4, 32);
        INS5(b0, b1, b2, b3, b4, o0); INS5(b0, b1, b2, b3, b4, o1);
        INS5(b0, b1, b2, b3, b4, o2); INS5(b0, b1, b2, b3, b4, o3);
        INS5(b0, b1, b2, b3, b4, o4);
    }
    if (h == 0) {
        float* p = pstats + ((size_t)ch * N_ROWS + i_lane) * 8;
        p[0] = s_run; p[1] = b0; p[2] = b1; p[3] = b2; p[4] = b3; p[5] = b4;
        p[6] = 0.f; p[7] = 0.f;
    }
}

// ---------------- K3: per-row merge of 8 chunk partials ----------------
__global__ __launch_bounds__(128) void reduce1(const float* __restrict__ pstats,
                                               float* __restrict__ partial) {
    int row = blockIdx.x * 128 + threadIdx.x;
    float S = 0.f;
    float b0 = NEG_BIG, b1 = NEG_BIG, b2 = NEG_BIG, b3 = NEG_BIG, b4 = NEG_BIG;
#pragma unroll
    for (int c = 0; c < NCHUNK; ++c) {
        const float* p = pstats + ((size_t)c * N_ROWS + row) * 8;
        S += p[0];
        float v0 = p[1], v1 = p[2], v2 = p[3], v3 = p[4], v4 = p[5];
        INS5(b0, b1, b2, b3, b4, v0); INS5(b0, b1, b2, b3, b4, v1);
        INS5(b0, b1, b2, b3, b4, v2); INS5(b0, b1, b2, b3, b4, v3);
        INS5(b0, b1, b2, b3, b4, v4);
    }
    float S5 = EXPV(b0) + EXPV(b1) + EXPV(b2) + EXPV(b3) + EXPV(b4);
    float loss = __logf(S) - __logf(S5);
#pragma unroll
    for (int m = 1; m < 64; m <<= 1) loss += __shfl_xor(loss, m);
    __shared__ float rr[2];
    if ((threadIdx.x & 63) == 0) rr[threadIdx.x >> 6] = loss;
    __syncthreads();
    if (threadIdx.x == 0) partial[blockIdx.x] = rr[0] + rr[1];
}

// ---------------- K4: final mean ----------------
__global__ void reduce2(const float* __restrict__ partial, float* __restrict__ out) {
    float v = partial[threadIdx.x];   // 64 partials
#pragma unroll
    for (int m = 1; m < 64; m <<= 1) v += __shfl_xor(v, m);
    if (threadIdx.x == 0) out[0] = v * (1.0f / N_ROWS);
}

extern "C" void kernel_launch(void* const* d_in, const int* in_sizes, int n_in,
                              void* d_out, int out_size, void* d_ws, size_t ws_size,
                              hipStream_t stream) {
    const float* z = (const float*)d_in[0];
    float* out = (float*)d_out;
    uint8_t* zn8   = (uint8_t*)d_ws;                                   // 8 MB
    float* pstats  = (float*)((char*)d_ws + (size_t)8 * 1024 * 1024);  // 2 MB
    float* partial = (float*)((char*)d_ws + (size_t)10 * 1024 * 1024); // 256 B

    norm_kernel<<<N_ROWS / 4, 256, 0, stream>>>(z, zn8);
    sim_kernel<<<64 * NCHUNK, 256, 0, stream>>>(zn8, pstats);
    reduce1<<<N_ROWS / 128, 128, 0, stream>>>(pstats, partial);
    reduce2<<<1, 64, 0, stream>>>(partial, out);
}